// Round 5
// baseline (599.544 us; speedup 1.0000x reference)
//
#include <hip/hip_runtime.h>

// Winograd F(4x4,3x3), fp32 in/out. x:[16,64,130,130] w:[64,64,3,3] -> y:[16,64,128,128]
// 3-kernel pipeline, M intermediate ELIMINATED:
//   k_filter: U = GwG^T  -> split-bf16 planes Uhi/Ulo [ab][k][c]
//   k_input2: V = B^T d B -> split-bf16 planes Vhi/Vlo [ab][p][c]
//   k_fused : per (64k x 16p) tile, loop 36 ab: MFMA(bf16 split: hh+hl+lh) GEMM over c,
//             fold M-tile into Y via sparse A_T x A_T coeffs, write y directly.
// Precision: hi+lo bf16 split reproduces fp32 to ~2^-17 relative; dropped lo*lo ~2^-18.
// ws: Uhi(295KB) | Ulo | Vhi(75.5MB) | Vlo  = 151.6 MB total.

typedef __attribute__((ext_vector_type(8))) short bf16x8;
typedef __attribute__((ext_vector_type(4))) float f32x4;

__device__ __forceinline__ unsigned short f2bf(float x) {
  unsigned u = __float_as_uint(x);
  u = u + 0x7fffu + ((u >> 16) & 1u);           // round-to-nearest-even
  return (unsigned short)(u >> 16);
}
__device__ __forceinline__ float bf2f(unsigned short h) {
  return __uint_as_float(((unsigned)h) << 16);
}

// ---------------- K0: filter transform U = G w G^T -> Uhi/Ulo [ab][k][c] ----------------
__global__ __launch_bounds__(256) void k_filter(const float* __restrict__ w,
                                                unsigned short* __restrict__ Uhi,
                                                unsigned short* __restrict__ Ulo) {
  int g = blockIdx.x * 256 + threadIdx.x;     // 0..4095
  int k = g & 63;
  int c = g >> 6;
  const float* wp = w + (size_t)(k * 64 + c) * 9;
  float w00 = wp[0], w01 = wp[1], w02 = wp[2];
  float w10 = wp[3], w11 = wp[4], w12 = wp[5];
  float w20 = wp[6], w21 = wp[7], w22 = wp[8];
  const float G[6][3] = {
    {0.25f, 0.f, 0.f},
    {-1.f/6.f, -1.f/6.f, -1.f/6.f},
    {-1.f/6.f,  1.f/6.f, -1.f/6.f},
    {1.f/24.f,  1.f/12.f, 1.f/6.f},
    {1.f/24.f, -1.f/12.f, 1.f/6.f},
    {0.f, 0.f, 1.f}
  };
  float t[6][3];
#pragma unroll
  for (int a = 0; a < 6; ++a) {
    t[a][0] = G[a][0]*w00 + G[a][1]*w10 + G[a][2]*w20;
    t[a][1] = G[a][0]*w01 + G[a][1]*w11 + G[a][2]*w21;
    t[a][2] = G[a][0]*w02 + G[a][1]*w12 + G[a][2]*w22;
  }
#pragma unroll
  for (int a = 0; a < 6; ++a) {
#pragma unroll
    for (int b = 0; b < 6; ++b) {
      float u = G[b][0]*t[a][0] + G[b][1]*t[a][1] + G[b][2]*t[a][2];
      unsigned short hi = f2bf(u);
      unsigned short lo = f2bf(u - bf2f(hi));
      size_t e = ((size_t)(a*6 + b) * 64 + k) * 64 + c;
      Uhi[e] = hi; Ulo[e] = lo;
    }
  }
}

// ---------------- K1: input transform V = B^T d B -> Vhi/Vlo [ab][p][c] ----------------
// block = (nl, ty): 32 p (tx 0..31) x 64 c in 4 chunks of 16 c.
// LDS stages x[16c][6 rows][130 cols]; each thread transforms 2 (c,p) pairs per chunk.
__global__ __launch_bounds__(256) void k_input2(const float* __restrict__ x,
                                                unsigned short* __restrict__ Vhi,
                                                unsigned short* __restrict__ Vlo) {
  __shared__ float Ls[16*6*132];               // 50688 B
  const int tid = threadIdx.x;
  const int nl  = blockIdx.x >> 5;
  const int ty  = blockIdx.x & 31;
  const int cl  = tid & 15;
  const int tx0 = tid >> 4;                    // 0..15

  for (int cg = 0; cg < 4; ++cg) {
    if (cg) __syncthreads();                   // retire previous chunk's reads
    for (int idx = tid; idx < 16*6*65; idx += 256) {
      int c16 = idx / 390;                     // 390 = 6*65
      int rem = idx - c16 * 390;
      int r   = rem / 65;
      int c2  = rem - r * 65;
      const float* src = x + ((size_t)((nl*64 + cg*16 + c16) * 130 + (ty*4 + r))) * 130 + c2*2;
      *(float2*)&Ls[(c16*6 + r)*132 + c2*2] = *(const float2*)src;
    }
    __syncthreads();
    const int cc = cg*16 + cl;
#pragma unroll
    for (int h = 0; h < 2; ++h) {
      const int tx = tx0 + h*16;
      const int p  = (nl*32 + ty)*32 + tx;
      const float* bl = &Ls[(cl*6)*132 + tx*4];
      float t1[6][6];
#pragma unroll
      for (int j = 0; j < 6; ++j) {            // t1 = B^T d
        float d0 = bl[0*132+j], d1 = bl[1*132+j], d2 = bl[2*132+j];
        float d3 = bl[3*132+j], d4 = bl[4*132+j], d5 = bl[5*132+j];
        t1[0][j] =  4.f*d0 - 5.f*d2 + d4;
        t1[1][j] = -4.f*d1 - 4.f*d2 + d3 + d4;
        t1[2][j] =  4.f*d1 - 4.f*d2 - d3 + d4;
        t1[3][j] = -2.f*d1 -     d2 + 2.f*d3 + d4;
        t1[4][j] =  2.f*d1 -     d2 - 2.f*d3 + d4;
        t1[5][j] =  4.f*d1 - 5.f*d3 + d5;
      }
#pragma unroll
      for (int a = 0; a < 6; ++a) {            // V = t1 * B
        float s0=t1[a][0], s1=t1[a][1], s2=t1[a][2], s3=t1[a][3], s4=t1[a][4], s5=t1[a][5];
        float vv[6];
        vv[0] =  4.f*s0 - 5.f*s2 + s4;
        vv[1] = -4.f*s1 - 4.f*s2 + s3 + s4;
        vv[2] =  4.f*s1 - 4.f*s2 - s3 + s4;
        vv[3] = -2.f*s1 -     s2 + 2.f*s3 + s4;
        vv[4] =  2.f*s1 -     s2 - 2.f*s3 + s4;
        vv[5] =  4.f*s1 - 5.f*s3 + s5;
#pragma unroll
        for (int b = 0; b < 6; ++b) {
          unsigned short hi = f2bf(vv[b]);
          unsigned short lo = f2bf(vv[b] - bf2f(hi));
          size_t e = ((size_t)(a*6 + b) * 16384 + p) * 64 + cc;
          Vhi[e] = hi; Vlo[e] = lo;
        }
      }
    }
  }
}

// ---------------- K2: fused GEMM + output transform ----------------
// block = 16-p tile, 4 waves = 64 k. Per ab: stage U[ab] (16KB) + V[ab][p-tile] (4KB)
// via reg-staging into padded LDS (144B rows -> 2-way-max bank conflicts),
// 6 MFMA (2 K-steps x {hh,hl,lh}), fold M into Y[4][16] with sparse AT coeffs.
// Double-buffered; one __syncthreads per ab; no hand-written waitcnt anywhere.
__global__ __launch_bounds__(256) void k_fused(const unsigned short* __restrict__ Uhi,
                                               const unsigned short* __restrict__ Ulo,
                                               const unsigned short* __restrict__ Vhi,
                                               const unsigned short* __restrict__ Vlo,
                                               float* __restrict__ out) {
  // per buffer: UhiL 64*144 | UloL 64*144 | VhiL 16*144 | VloL 16*144 = 23040 B
  __shared__ __align__(16) float LdsF[2*23040/4];
  char* Lds = (char*)LdsF;
  const int tid  = threadIdx.x;
  const int lane = tid & 63;
  const int wv   = tid >> 6;
  const int p0   = blockIdx.x * 16;

  // 5 staging chunks/thread: [0,1]=Uhi, [2,3]=Ulo, [4]=Vhi(tid<128)/Vlo
  const char* gb[5]; size_t gst[5]; int lo_[5];
  {
    int q0 = tid, q1 = tid + 256;
    gb[0] = (const char*)Uhi + q0*16; gst[0] = 8192; lo_[0] =        (q0>>3)*144 + (q0&7)*16;
    gb[1] = (const char*)Uhi + q1*16; gst[1] = 8192; lo_[1] =        (q1>>3)*144 + (q1&7)*16;
    gb[2] = (const char*)Ulo + q0*16; gst[2] = 8192; lo_[2] = 9216 + (q0>>3)*144 + (q0&7)*16;
    gb[3] = (const char*)Ulo + q1*16; gst[3] = 8192; lo_[3] = 9216 + (q1>>3)*144 + (q1&7)*16;
    if (tid < 128) {
      int q = tid;
      gb[4] = (const char*)Vhi + (size_t)(p0 + (q>>3))*128 + (q&7)*16;
      gst[4] = (size_t)16384*128; lo_[4] = 18432 + (q>>3)*144 + (q&7)*16;
    } else {
      int q = tid - 128;
      gb[4] = (const char*)Vlo + (size_t)(p0 + (q>>3))*128 + (q&7)*16;
      gst[4] = (size_t)16384*128; lo_[4] = 20736 + (q>>3)*144 + (q&7)*16;
    }
  }

  float Yv[4][16];
#pragma unroll
  for (int r = 0; r < 4; ++r)
#pragma unroll
    for (int q = 0; q < 16; ++q) Yv[r][q] = 0.f;

  const float AT4[4][6] = {
    {1.f, 1.f,  1.f, 1.f,  1.f, 0.f},
    {0.f, 1.f, -1.f, 2.f, -2.f, 0.f},
    {0.f, 1.f,  1.f, 4.f,  4.f, 0.f},
    {0.f, 1.f, -1.f, 8.f, -8.f, 1.f}
  };

  // prologue: stage ab=0 into buffer 0
  {
    float4 s0[5];
#pragma unroll
    for (int i = 0; i < 5; ++i) s0[i] = *(const float4*)(gb[i]);
#pragma unroll
    for (int i = 0; i < 5; ++i) *(float4*)(Lds + lo_[i]) = s0[i];
  }
  __syncthreads();

  int bsel = 0;
#pragma unroll
  for (int a6 = 0; a6 < 6; ++a6) {
#pragma unroll
    for (int b6 = 0; b6 < 6; ++b6) {
      const int ab = a6*6 + b6;
      float4 sreg[5];
      if (ab < 35) {                            // prefetch next ab (global -> regs)
#pragma unroll
        for (int i = 0; i < 5; ++i)
          sreg[i] = *(const float4*)(gb[i] + (size_t)(ab + 1) * gst[i]);
      }
      const char* B0 = Lds + bsel*23040;
      f32x4 m4 = {0.f, 0.f, 0.f, 0.f};
      const int arow = wv*16 + (lane & 15);
      const int brow = (lane & 15);
#pragma unroll
      for (int s = 0; s < 2; ++s) {
        const int g = (lane >> 4) + 4*s;        // c-group: c = g*8..g*8+7
        bf16x8 ah  = *(const bf16x8*)(B0 +         arow*144 + g*16);
        bf16x8 al  = *(const bf16x8*)(B0 +  9216 + arow*144 + g*16);
        bf16x8 bh  = *(const bf16x8*)(B0 + 18432 + brow*144 + g*16);
        bf16x8 bl2 = *(const bf16x8*)(B0 + 20736 + brow*144 + g*16);
        m4 = __builtin_amdgcn_mfma_f32_16x16x32_bf16(ah, bh,  m4, 0, 0, 0);
        m4 = __builtin_amdgcn_mfma_f32_16x16x32_bf16(ah, bl2, m4, 0, 0, 0);
        m4 = __builtin_amdgcn_mfma_f32_16x16x32_bf16(al, bh,  m4, 0, 0, 0);
      }
      // fold M-tile into Y: Y[u][v] += AT[u][a6]*AT[v][b6]*M  (zeros folded away)
#pragma unroll
      for (int u = 0; u < 4; ++u) {
        const float cu = AT4[u][a6];
        if (cu == 0.f) continue;
#pragma unroll
        for (int v = 0; v < 4; ++v) {
          const float cv = AT4[v][b6];
          if (cv == 0.f) continue;
          const float cf = cu * cv;
#pragma unroll
          for (int r = 0; r < 4; ++r) Yv[r][u*4 + v] += cf * m4[r];
        }
      }
      if (ab < 35) {                            // commit prefetch into other buffer
        char* W0 = Lds + (bsel^1)*23040;
#pragma unroll
        for (int i = 0; i < 5; ++i) *(float4*)(W0 + lo_[i]) = sreg[i];
      }
      __syncthreads();
      bsel ^= 1;
    }
  }

  // epilogue: C/D layout col=lane&15 (=p), row=(lane>>4)*4+r (=k within wave)
  const int p  = p0 + (lane & 15);
  const int n  = p >> 10;
  const int ty = (p >> 5) & 31;
  const int tx = p & 31;
#pragma unroll
  for (int r = 0; r < 4; ++r) {
    const int k = wv*16 + (lane >> 4)*4 + r;
    float* ob = out + ((size_t)(n*64 + k)*128 + ty*4)*128 + tx*4;
#pragma unroll
    for (int u = 0; u < 4; ++u)
      *(float4*)(ob + (size_t)u*128) =
        make_float4(Yv[r][u*4+0], Yv[r][u*4+1], Yv[r][u*4+2], Yv[r][u*4+3]);
  }
}

extern "C" void kernel_launch(void* const* d_in, const int* in_sizes, int n_in,
                              void* d_out, int out_size, void* d_ws, size_t ws_size,
                              hipStream_t stream) {
  const float* x = (const float*)d_in[0];
  const float* w = (const float*)d_in[1];
  float* out = (float*)d_out;

  unsigned short* Uhi = (unsigned short*)d_ws;
  unsigned short* Ulo = Uhi + (size_t)36*64*64;          // 147456 elems
  unsigned short* Vhi = Ulo + (size_t)36*64*64;
  unsigned short* Vlo = Vhi + (size_t)36*16384*64;       // 37748736 elems

  const size_t need = (2ull*36*64*64 + 2ull*36*16384*64) * 2;  // 151584768 B
  if (ws_size < need) return;

  k_filter<<<16,   256, 0, stream>>>(w, Uhi, Ulo);
  k_input2<<<512,  256, 0, stream>>>(x, Vhi, Vlo);
  k_fused <<<1024, 256, 0, stream>>>(Uhi, Ulo, Vhi, Vlo, out);
}